// Round 4
// baseline (1012.207 us; speedup 1.0000x reference)
//
#include <hip/hip_runtime.h>

// ---------- types ----------
typedef __bf16 bf16_t;
typedef bf16_t bf16x8 __attribute__((ext_vector_type(8)));
typedef float f32x4 __attribute__((ext_vector_type(4)));

__device__ inline f32x4 mfma16(bf16x8 a, bf16x8 b, f32x4 c) {
    return __builtin_amdgcn_mfma_f32_16x16x32_bf16(a, b, c, 0, 0, 0);
}

__device__ inline ushort f2bf(float f) {
    unsigned u = __builtin_bit_cast(unsigned, f);
    unsigned r = (u + 0x7FFFu + ((u >> 16) & 1u)) >> 16;
    return (ushort)r;
}

__device__ inline void gload_lds16(const void* g, void* l) {
    __builtin_amdgcn_global_load_lds(
        (const __attribute__((address_space(1))) void*)g,
        (__attribute__((address_space(3))) void*)l, 16, 0, 0);
}

// ---------- problem constants ----------
// B=16, Ktok=1024, D=512, HS=2048, HR=1024, E=8
// M = 16384, units: 0,1 = shared halves (scale 1), 2..9 = experts (scale rw[b,e])
#define M_TOT 16384
#define D_DIM 512
#define H_UNIT 1024
#define N_UNITS 10
#define UNIT_W_ELEMS (1024*512)

// ---------- conversion kernels ----------
__global__ void k_cvt_x(const float* __restrict__ x, ushort* __restrict__ xb) {
    int i = (blockIdx.x * 256 + threadIdx.x) * 4;
    float4 v = *reinterpret_cast<const float4*>(x + i);
    ushort4 o;
    o.x = f2bf(v.x); o.y = f2bf(v.y); o.z = f2bf(v.z); o.w = f2bf(v.w);
    *reinterpret_cast<ushort4*>(xb + i) = o;
}

// transpose [ROWS x COLS] f32 submatrix (per unit) -> [COLS x ROWS] bf16
template<int ROWS, int COLS, int MODE>
__global__ void k_trans(const float* __restrict__ Wsh, const float* __restrict__ Wrt,
                        ushort* __restrict__ dst) {
    int u = blockIdx.z;
    const float* src; int stride;
    if (MODE == 0) {
        if (u < 2) { src = Wsh + u * COLS; stride = 2 * COLS; }
        else       { src = Wrt + (size_t)(u - 2) * ROWS * COLS; stride = COLS; }
    } else {
        src = (u < 2) ? (Wsh + (size_t)u * ROWS * COLS)
                      : (Wrt + (size_t)(u - 2) * ROWS * COLS);
        stride = COLS;
    }
    __shared__ float t[64][65];
    int r0 = blockIdx.y * 64, c0 = blockIdx.x * 64;
    int tid = threadIdx.x;
#pragma unroll
    for (int i = 0; i < 16; ++i) {
        int idx = i * 256 + tid;
        int r = idx >> 6, c = idx & 63;
        t[r][c] = src[(r0 + r) * stride + c0 + c];
    }
    __syncthreads();
    ushort* d = dst + (size_t)u * ROWS * COLS;
#pragma unroll
    for (int i = 0; i < 16; ++i) {
        int idx = i * 256 + tid;
        int r = idx >> 6, c = idx & 63;
        d[(c0 + r) * ROWS + (r0 + c)] = f2bf(t[c][r]);
    }
}

// out[m][d] = bs_down[d] + sum_e rw[b][e]*br_down[e][d]   (fallback path only)
__global__ void k_init_out(const float* __restrict__ bsd, const float* __restrict__ brd,
                           const float* __restrict__ rw, float* __restrict__ out) {
    int i = (blockIdx.x * 256 + threadIdx.x) * 4;
    int d = i & 511;
    int m = i >> 9;
    int b = m >> 10;
    float4 v = *reinterpret_cast<const float4*>(bsd + d);
#pragma unroll
    for (int e = 0; e < 8; ++e) {
        float w = rw[b * 8 + e];
        float4 bb = *reinterpret_cast<const float4*>(brd + e * 512 + d);
        v.x += w * bb.x; v.y += w * bb.y; v.z += w * bb.z; v.w += w * bb.w;
    }
    *reinterpret_cast<float4*>(out + i) = v;
}

// ---------- GEMM 1 (fused, all units): gate+up+SwiGLU ----------
// A [M][512] bf16, WG/WU [10][1024][512] bf16 N-major, Hall [10][M][1024] bf16
// grid = 10240 blocks (1D), XCD-swizzled; 128x128 tile, BK=32, 4 waves.
__global__ __launch_bounds__(256, 2) void gemm_gateup_all(
    const ushort* __restrict__ A, const ushort* __restrict__ WG, const ushort* __restrict__ WU,
    const float* __restrict__ bsg, const float* __restrict__ bsu,
    const float* __restrict__ brg, const float* __restrict__ bru,
    const float* __restrict__ rw, ushort* __restrict__ Hall) {
    constexpr int K = 512, N = 1024;
    __shared__ ushort lsA[128 * 32];
    __shared__ ushort lsG[128 * 32];
    __shared__ ushort lsU[128 * 32];
    // bijective XCD swizzle: nwg=10240, 10240/8=1280
    int lid = blockIdx.x;
    int swz = (lid & 7) * 1280 + (lid >> 3);
    const int u = swz >> 10;              // unit 0..9
    const int rem = swz & 1023;
    const int bm = (rem >> 3) * 128;      // 128 M-tiles
    const int bn = (rem & 7) * 128;       // 8 N-tiles
    const ushort* Bg = WG + (size_t)u * UNIT_W_ELEMS;
    const ushort* Bu = WU + (size_t)u * UNIT_W_ELEMS;

    const int tid = threadIdx.x;
    const int l = tid & 63, w = tid >> 6;
    const int wm = w >> 1, wn = w & 1;

    f32x4 accg[4][4] = {};
    f32x4 accu[4][4] = {};

    for (int kk = 0; kk < K; kk += 32) {
#pragma unroll
        for (int j = 0; j < 2; ++j) {
            int q = w * 2 + j;
            int c = q * 64 + l;
            int row = c >> 2, cw = c & 3;
            int ga = (bm + row) * K + kk + cw * 8;
            int gb = (bn + row) * K + kk + cw * 8;
            gload_lds16(A + ga, lsA + q * 512);
            gload_lds16(Bg + gb, lsG + q * 512);
            gload_lds16(Bu + gb, lsU + q * 512);
        }
        __syncthreads();
        bf16x8 af[4], gf[4], uf[4];
#pragma unroll
        for (int i = 0; i < 4; ++i) {
            int ar = wm * 64 + i * 16 + (l & 15);
            int br = wn * 64 + i * 16 + (l & 15);
            af[i] = *reinterpret_cast<const bf16x8*>(&lsA[ar * 32 + (l >> 4) * 8]);
            gf[i] = *reinterpret_cast<const bf16x8*>(&lsG[br * 32 + (l >> 4) * 8]);
            uf[i] = *reinterpret_cast<const bf16x8*>(&lsU[br * 32 + (l >> 4) * 8]);
        }
#pragma unroll
        for (int mi = 0; mi < 4; ++mi)
#pragma unroll
            for (int ni = 0; ni < 4; ++ni) {
                accg[mi][ni] = mfma16(af[mi], gf[ni], accg[mi][ni]);
                accu[mi][ni] = mfma16(af[mi], uf[ni], accu[mi][ni]);
            }
        __syncthreads();
    }

    const float* bg = (u < 2) ? (bsg + u * 1024) : (brg + (u - 2) * 1024);
    const float* bu = (u < 2) ? (bsu + u * 1024) : (bru + (u - 2) * 1024);
    const float scale = (u < 2) ? 1.0f : rw[(bm >> 10) * 8 + (u - 2)];
    ushort* H = Hall + (size_t)u * M_TOT * H_UNIT;
#pragma unroll
    for (int ni = 0; ni < 4; ++ni) {
        int col = bn + wn * 64 + ni * 16 + (l & 15);
        float bgv = bg[col], buv = bu[col];
#pragma unroll
        for (int mi = 0; mi < 4; ++mi)
#pragma unroll
            for (int r = 0; r < 4; ++r) {
                int row = bm + wm * 64 + mi * 16 + (l >> 4) * 4 + r;
                float g = accg[mi][ni][r] + bgv;
                float uu = accu[mi][ni][r] + buv;
                float h = g / (1.0f + __expf(-g)) * uu * scale;
                H[row * N + col] = f2bf(h);
            }
    }
}

// ---------- GEMM 2 (fused, all units): down, K=10240, bias fold, single write ----------
// A = Hall [10][M][1024] bf16, WD [10][512][1024] bf16 N-major, out [M][512] f32
__global__ __launch_bounds__(256, 2) void gemm_down_all(
    const ushort* __restrict__ Hall, const ushort* __restrict__ WD,
    const float* __restrict__ bsd, const float* __restrict__ brd,
    const float* __restrict__ rw, float* __restrict__ out) {
    constexpr int N = 512;
    __shared__ ushort lsA[128 * 32];
    __shared__ ushort lsB[128 * 32];
    // bijective XCD swizzle: nwg=512, 512/8=64
    int lid = blockIdx.x;
    int swz = (lid & 7) * 64 + (lid >> 3);
    const int bm = (swz >> 2) * 128;   // 128 M-tiles
    const int bn = (swz & 3) * 128;    // 4 N-tiles

    const int tid = threadIdx.x;
    const int l = tid & 63, w = tid >> 6;
    const int wm = w >> 1, wn = w & 1;

    f32x4 acc[4][4] = {};

    for (int u = 0; u < N_UNITS; ++u) {
        const ushort* Au = Hall + (size_t)u * M_TOT * H_UNIT;
        const ushort* Bu = WD + (size_t)u * UNIT_W_ELEMS;
        for (int kk = 0; kk < 1024; kk += 32) {
#pragma unroll
            for (int j = 0; j < 2; ++j) {
                int q = w * 2 + j;
                int c = q * 64 + l;
                int row = c >> 2, cw = c & 3;
                int ga = (bm + row) * 1024 + kk + cw * 8;
                int gb = (bn + row) * 1024 + kk + cw * 8;
                gload_lds16(Au + ga, lsA + q * 512);
                gload_lds16(Bu + gb, lsB + q * 512);
            }
            __syncthreads();
            bf16x8 af[4], bfr[4];
#pragma unroll
            for (int i = 0; i < 4; ++i) {
                int ar = wm * 64 + i * 16 + (l & 15);
                int br = wn * 64 + i * 16 + (l & 15);
                af[i] = *reinterpret_cast<const bf16x8*>(&lsA[ar * 32 + (l >> 4) * 8]);
                bfr[i] = *reinterpret_cast<const bf16x8*>(&lsB[br * 32 + (l >> 4) * 8]);
            }
#pragma unroll
            for (int mi = 0; mi < 4; ++mi)
#pragma unroll
                for (int ni = 0; ni < 4; ++ni)
                    acc[mi][ni] = mfma16(af[mi], bfr[ni], acc[mi][ni]);
            __syncthreads();
        }
    }

    const int b = bm >> 10;
#pragma unroll
    for (int ni = 0; ni < 4; ++ni) {
        int col = bn + wn * 64 + ni * 16 + (l & 15);
        float bias = bsd[col];
#pragma unroll
        for (int e = 0; e < 8; ++e)
            bias += rw[b * 8 + e] * brd[e * 512 + col];
#pragma unroll
        for (int mi = 0; mi < 4; ++mi)
#pragma unroll
            for (int r = 0; r < 4; ++r) {
                int row = bm + wm * 64 + mi * 16 + (l >> 4) * 4 + r;
                out[row * N + col] = acc[mi][ni][r] + bias;
            }
    }
}

// ---------- fallback per-unit GEMMs (round-2 proven path) ----------
__global__ __launch_bounds__(256, 2) void gemm_gateup(
    const ushort* __restrict__ A, const ushort* __restrict__ Bg, const ushort* __restrict__ Bu,
    const float* __restrict__ bg, const float* __restrict__ bu,
    const float* __restrict__ rw, ushort* __restrict__ H, int e_idx) {
    constexpr int K = 512, N = 1024;
    __shared__ ushort lsA[128 * 32];
    __shared__ ushort lsG[128 * 32];
    __shared__ ushort lsU[128 * 32];
    const int tid = threadIdx.x;
    const int l = tid & 63, w = tid >> 6;
    const int wm = w >> 1, wn = w & 1;
    const int bm = blockIdx.y * 128, bn = blockIdx.x * 128;

    f32x4 accg[4][4] = {};
    f32x4 accu[4][4] = {};

    for (int kk = 0; kk < K; kk += 32) {
#pragma unroll
        for (int j = 0; j < 2; ++j) {
            int q = w * 2 + j;
            int c = q * 64 + l;
            int row = c >> 2, cw = c & 3;
            int ga = (bm + row) * K + kk + cw * 8;
            int gb = (bn + row) * K + kk + cw * 8;
            gload_lds16(A + ga, lsA + q * 512);
            gload_lds16(Bg + gb, lsG + q * 512);
            gload_lds16(Bu + gb, lsU + q * 512);
        }
        __syncthreads();
        bf16x8 af[4], gf[4], uf[4];
#pragma unroll
        for (int i = 0; i < 4; ++i) {
            int ar = wm * 64 + i * 16 + (l & 15);
            int br = wn * 64 + i * 16 + (l & 15);
            af[i] = *reinterpret_cast<const bf16x8*>(&lsA[ar * 32 + (l >> 4) * 8]);
            gf[i] = *reinterpret_cast<const bf16x8*>(&lsG[br * 32 + (l >> 4) * 8]);
            uf[i] = *reinterpret_cast<const bf16x8*>(&lsU[br * 32 + (l >> 4) * 8]);
        }
#pragma unroll
        for (int mi = 0; mi < 4; ++mi)
#pragma unroll
            for (int ni = 0; ni < 4; ++ni) {
                accg[mi][ni] = mfma16(af[mi], gf[ni], accg[mi][ni]);
                accu[mi][ni] = mfma16(af[mi], uf[ni], accu[mi][ni]);
            }
        __syncthreads();
    }

    const float scale = (e_idx < 0) ? 1.0f : rw[(bm >> 10) * 8 + e_idx];
#pragma unroll
    for (int ni = 0; ni < 4; ++ni) {
        int col = bn + wn * 64 + ni * 16 + (l & 15);
        float bgv = bg[col], buv = bu[col];
#pragma unroll
        for (int mi = 0; mi < 4; ++mi)
#pragma unroll
            for (int r = 0; r < 4; ++r) {
                int row = bm + wm * 64 + mi * 16 + (l >> 4) * 4 + r;
                float g = accg[mi][ni][r] + bgv;
                float u = accu[mi][ni][r] + buv;
                float h = g / (1.0f + __expf(-g)) * u * scale;
                H[row * N + col] = f2bf(h);
            }
    }
}

__global__ __launch_bounds__(256, 2) void gemm_down(
    const ushort* __restrict__ A, const ushort* __restrict__ Bt,
    float* __restrict__ out) {
    constexpr int K = 1024, N = 512;
    __shared__ ushort lsA[128 * 32];
    __shared__ ushort lsB[128 * 32];
    const int tid = threadIdx.x;
    const int l = tid & 63, w = tid >> 6;
    const int wm = w >> 1, wn = w & 1;
    const int bm = blockIdx.y * 128, bn = blockIdx.x * 128;

    f32x4 acc[4][4] = {};

    for (int kk = 0; kk < K; kk += 32) {
#pragma unroll
        for (int j = 0; j < 2; ++j) {
            int q = w * 2 + j;
            int c = q * 64 + l;
            int row = c >> 2, cw = c & 3;
            int ga = (bm + row) * K + kk + cw * 8;
            int gb = (bn + row) * K + kk + cw * 8;
            gload_lds16(A + ga, lsA + q * 512);
            gload_lds16(Bt + gb, lsB + q * 512);
        }
        __syncthreads();
        bf16x8 af[4], bfr[4];
#pragma unroll
        for (int i = 0; i < 4; ++i) {
            int ar = wm * 64 + i * 16 + (l & 15);
            int br = wn * 64 + i * 16 + (l & 15);
            af[i] = *reinterpret_cast<const bf16x8*>(&lsA[ar * 32 + (l >> 4) * 8]);
            bfr[i] = *reinterpret_cast<const bf16x8*>(&lsB[br * 32 + (l >> 4) * 8]);
        }
#pragma unroll
        for (int mi = 0; mi < 4; ++mi)
#pragma unroll
            for (int ni = 0; ni < 4; ++ni)
                acc[mi][ni] = mfma16(af[mi], bfr[ni], acc[mi][ni]);
        __syncthreads();
    }

#pragma unroll
    for (int ni = 0; ni < 4; ++ni) {
        int col = bn + wn * 64 + ni * 16 + (l & 15);
#pragma unroll
        for (int mi = 0; mi < 4; ++mi)
#pragma unroll
            for (int r = 0; r < 4; ++r) {
                int row = bm + wm * 64 + mi * 16 + (l >> 4) * 4 + r;
                out[row * N + col] += acc[mi][ni][r];
            }
    }
}

// ---------- launch ----------
extern "C" void kernel_launch(void* const* d_in, const int* in_sizes, int n_in,
                              void* d_out, int out_size, void* d_ws, size_t ws_size,
                              hipStream_t stream) {
    const float* x   = (const float*)d_in[0];
    const float* rw  = (const float*)d_in[1];
    const float* Wsg = (const float*)d_in[2];
    const float* bsg = (const float*)d_in[3];
    const float* Wsu = (const float*)d_in[4];
    const float* bsu = (const float*)d_in[5];
    const float* Wsd = (const float*)d_in[6];
    const float* bsd = (const float*)d_in[7];
    const float* Wrg = (const float*)d_in[8];
    const float* brg = (const float*)d_in[9];
    const float* Wru = (const float*)d_in[10];
    const float* bru = (const float*)d_in[11];
    const float* Wrd = (const float*)d_in[12];
    const float* brd = (const float*)d_in[13];
    float* out = (float*)d_out;

    const size_t xb_b  = (size_t)M_TOT * D_DIM * 2;
    const size_t w_b   = (size_t)N_UNITS * UNIT_W_ELEMS * 2;
    const size_t hall_b = (size_t)N_UNITS * M_TOT * H_UNIT * 2;

    char* ws = (char*)d_ws;
    ushort* xb  = (ushort*)ws; ws += xb_b;
    ushort* wgT = (ushort*)ws; ws += w_b;
    ushort* wuT = (ushort*)ws; ws += w_b;
    ushort* wdT = (ushort*)ws; ws += w_b;
    ushort* Hb  = (ushort*)ws;  // fused: 335.5 MB; fallback: 33.5 MB

    const bool fused = (ws_size >= xb_b + 3 * w_b + hall_b);

    k_cvt_x<<<8192, 256, 0, stream>>>(x, xb);
    k_trans<512, 1024, 0><<<dim3(16, 8, 10), 256, 0, stream>>>(Wsg, Wrg, wgT);
    k_trans<512, 1024, 0><<<dim3(16, 8, 10), 256, 0, stream>>>(Wsu, Wru, wuT);
    k_trans<1024, 512, 1><<<dim3(8, 16, 10), 256, 0, stream>>>(Wsd, Wrd, wdT);

    if (fused) {
        gemm_gateup_all<<<10240, 256, 0, stream>>>(xb, wgT, wuT, bsg, bsu, brg, bru, rw, Hb);
        gemm_down_all<<<512, 256, 0, stream>>>(Hb, wdT, bsd, brd, rw, out);
    } else {
        k_init_out<<<8192, 256, 0, stream>>>(bsd, brd, rw, out);
        for (int u = 0; u < N_UNITS; ++u) {
            const ushort* wg = wgT + (size_t)u * UNIT_W_ELEMS;
            const ushort* wu = wuT + (size_t)u * UNIT_W_ELEMS;
            const ushort* wd = wdT + (size_t)u * UNIT_W_ELEMS;
            const float* bgB = (u < 2) ? (bsg + u * 1024) : (brg + (u - 2) * 1024);
            const float* buB = (u < 2) ? (bsu + u * 1024) : (bru + (u - 2) * 1024);
            int e_idx = (u < 2) ? -1 : (u - 2);
            gemm_gateup<<<dim3(8, 128), 256, 0, stream>>>(xb, wg, wu, bgB, buB, rw, Hb, e_idx);
            gemm_down<<<dim3(4, 128), 256, 0, stream>>>(Hb, wd, out);
        }
    }
}

// Round 11
// 759.496 us; speedup vs baseline: 1.3327x; 1.3327x over previous
//
#include <hip/hip_runtime.h>

// ---------- types ----------
typedef __bf16 bf16_t;
typedef bf16_t bf16x8 __attribute__((ext_vector_type(8)));
typedef float f32x4 __attribute__((ext_vector_type(4)));

__device__ inline f32x4 mfma16(bf16x8 a, bf16x8 b, f32x4 c) {
    return __builtin_amdgcn_mfma_f32_16x16x32_bf16(a, b, c, 0, 0, 0);
}

__device__ inline ushort f2bf(float f) {
    unsigned u = __builtin_bit_cast(unsigned, f);
    unsigned r = (u + 0x7FFFu + ((u >> 16) & 1u)) >> 16;
    return (ushort)r;
}

__device__ inline void gload_lds16(const void* g, void* l) {
    __builtin_amdgcn_global_load_lds(
        (const __attribute__((address_space(1))) void*)g,
        (__attribute__((address_space(3))) void*)l, 16, 0, 0);
}

// ---------- problem constants ----------
// B=16, Ktok=1024, D=512, HS=2048, HR=1024, E=8
// M=16384; units 0,1 = shared halves (scale 1), 2..9 = experts (scale rw[b,e])
#define M_TOT 16384
#define N_UNITS 10
#define UNIT_W (1024*512)

// ---------- conversion kernels ----------
__global__ void k_cvt_x(const float* __restrict__ x, ushort* __restrict__ xb) {
    int i = (blockIdx.x * 256 + threadIdx.x) * 4;
    float4 v = *reinterpret_cast<const float4*>(x + i);
    ushort4 o;
    o.x = f2bf(v.x); o.y = f2bf(v.y); o.z = f2bf(v.z); o.w = f2bf(v.w);
    *reinterpret_cast<ushort4*>(xb + i) = o;
}

// transpose [ROWS x COLS] f32 submatrix (per unit) -> [COLS x ROWS] bf16
template<int ROWS, int COLS, int MODE>
__global__ void k_trans(const float* __restrict__ Wsh, const float* __restrict__ Wrt,
                        ushort* __restrict__ dst) {
    int u = blockIdx.z;
    const float* src; int stride;
    if (MODE == 0) {
        if (u < 2) { src = Wsh + u * COLS; stride = 2 * COLS; }
        else       { src = Wrt + (size_t)(u - 2) * ROWS * COLS; stride = COLS; }
    } else {
        src = (u < 2) ? (Wsh + (size_t)u * ROWS * COLS)
                      : (Wrt + (size_t)(u - 2) * ROWS * COLS);
        stride = COLS;
    }
    __shared__ float t[64][65];
    int r0 = blockIdx.y * 64, c0 = blockIdx.x * 64;
    int tid = threadIdx.x;
#pragma unroll
    for (int i = 0; i < 16; ++i) {
        int idx = i * 256 + tid;
        int r = idx >> 6, c = idx & 63;
        t[r][c] = src[(r0 + r) * stride + c0 + c];
    }
    __syncthreads();
    ushort* d = dst + (size_t)u * ROWS * COLS;
#pragma unroll
    for (int i = 0; i < 16; ++i) {
        int idx = i * 256 + tid;
        int r = idx >> 6, c = idx & 63;
        d[(c0 + r) * ROWS + (r0 + c)] = f2bf(t[c][r]);
    }
}

// ---------- GEMM 1: gate+up+SwiGLU, BK=64, XOR-swizzled LDS ----------
// A [M_TOT][512] bf16; WG/WU [10][1024][512] bf16 N-major.
// Hall layout [n_units_in_dispatch][mc][1024]; grid = n_units * (mc/16); log2p = log2(mc/16).
__global__ __launch_bounds__(256, 2) void gemm_gateup2(
    const ushort* __restrict__ A, const ushort* __restrict__ WG, const ushort* __restrict__ WU,
    const float* __restrict__ bsg, const float* __restrict__ bsu,
    const float* __restrict__ brg, const float* __restrict__ bru,
    const float* __restrict__ rw, ushort* __restrict__ Hall,
    int unit_base, int m_base, int mc, int log2p) {
    __shared__ ushort lsA[128 * 64];
    __shared__ ushort lsG[128 * 64];
    __shared__ ushort lsU[128 * 64];
    const int nwg = gridDim.x, cpx = nwg >> 3;
    const int lid = blockIdx.x;
    const int swz = (lid & 7) * cpx + (lid >> 3);   // bijective: nwg % 8 == 0
    const int ul = swz >> log2p;
    const int rem = swz & ((1 << log2p) - 1);
    const int bm = (rem >> 3) * 128;   // local M row
    const int bn = (rem & 7) * 128;    // H col
    const int ug = unit_base + ul;
    const ushort* Bg = WG + (size_t)ug * UNIT_W;
    const ushort* Bu = WU + (size_t)ug * UNIT_W;

    const int tid = threadIdx.x;
    const int l = tid & 63, w = tid >> 6;
    const int wm = w >> 1, wn = w & 1;

    f32x4 accg[4][4] = {};
    f32x4 accu[4][4] = {};

    for (int kk = 0; kk < 512; kk += 64) {
#pragma unroll
        for (int j = 0; j < 4; ++j) {
            int q = w * 4 + j;            // 1KB block 0..15
            int c = q * 64 + l;           // 16B chunk 0..1023
            int row = c >> 3, pc = c & 7;
            int lc = pc ^ (row & 7);      // source k-chunk (inverse swizzle)
            int koff = kk + lc * 8;
            gload_lds16(A  + (size_t)(m_base + bm + row) * 512 + koff, lsA + q * 512);
            gload_lds16(Bg + (size_t)(bn + row) * 512 + koff,          lsG + q * 512);
            gload_lds16(Bu + (size_t)(bn + row) * 512 + koff,          lsU + q * 512);
        }
        __syncthreads();
#pragma unroll
        for (int s = 0; s < 2; ++s) {
            bf16x8 af[4], gf[4], uf[4];
#pragma unroll
            for (int i = 0; i < 4; ++i) {
                int ar = wm * 64 + i * 16 + (l & 15);
                int br = wn * 64 + i * 16 + (l & 15);
                int lcr = s * 4 + (l >> 4);
                af[i] = *reinterpret_cast<const bf16x8*>(&lsA[ar * 64 + ((lcr ^ (ar & 7)) * 8)]);
                gf[i] = *reinterpret_cast<const bf16x8*>(&lsG[br * 64 + ((lcr ^ (br & 7)) * 8)]);
                uf[i] = *reinterpret_cast<const bf16x8*>(&lsU[br * 64 + ((lcr ^ (br & 7)) * 8)]);
            }
#pragma unroll
            for (int mi = 0; mi < 4; ++mi)
#pragma unroll
                for (int ni = 0; ni < 4; ++ni) {
                    accg[mi][ni] = mfma16(af[mi], gf[ni], accg[mi][ni]);
                    accu[mi][ni] = mfma16(af[mi], uf[ni], accu[mi][ni]);
                }
        }
        __syncthreads();
    }

    const float* bg = (ug < 2) ? (bsg + ug * 1024) : (brg + (ug - 2) * 1024);
    const float* bu = (ug < 2) ? (bsu + ug * 1024) : (bru + (ug - 2) * 1024);
    const float scale = (ug < 2) ? 1.0f : rw[((m_base + bm) >> 10) * 8 + (ug - 2)];
    ushort* H = Hall + (size_t)ul * mc * 1024;
#pragma unroll
    for (int ni = 0; ni < 4; ++ni) {
        int col = bn + wn * 64 + ni * 16 + (l & 15);
        float bgv = bg[col], buv = bu[col];
#pragma unroll
        for (int mi = 0; mi < 4; ++mi)
#pragma unroll
            for (int r = 0; r < 4; ++r) {
                int lrow = bm + wm * 64 + mi * 16 + (l >> 4) * 4 + r;
                float g = accg[mi][ni][r] + bgv;
                float uu = accu[mi][ni][r] + buv;
                float h = g / (1.0f + __expf(-g)) * uu * scale;
                H[(size_t)lrow * 1024 + col] = f2bf(h);
            }
    }
}

// ---------- GEMM 2: down, multi-unit register-accumulated K, BK=64, swizzled ----------
// Hall [nu][mc][1024] bf16; WD [10][512][1024] bf16 N-major; out [M_TOT][512] f32.
// TN = N-tile (128 or 64). grid = (mc/128) * (512/TN), must be %8==0.
template<int TN>
__global__ __launch_bounds__(256, 2) void gemm_down2(
    const ushort* __restrict__ Hall, const ushort* __restrict__ WD,
    const float* __restrict__ bsd, const float* __restrict__ brd,
    const float* __restrict__ rw, float* __restrict__ out,
    int nu, int unit_base, int m_base, int mc, int accumulate) {
    constexpr int WN = TN / 2;        // per-wave N
    constexpr int NI = WN / 16;       // N fragments per wave
    constexpr int BCH = TN / 32;      // B staging chunks per thread
    constexpr int NBN = 512 / TN;     // N-blocks
    __shared__ ushort lsA[128 * 64];
    __shared__ ushort lsB[TN * 64];
    const int nwg = gridDim.x, cpx = nwg >> 3;
    const int lid = blockIdx.x;
    const int swz = (lid & 7) * cpx + (lid >> 3);
    const int bm = (swz / NBN) * 128;  // local M row
    const int bn = (swz % NBN) * TN;

    const int tid = threadIdx.x;
    const int l = tid & 63, w = tid >> 6;
    const int wm = w >> 1, wn = w & 1;

    f32x4 acc[4][NI] = {};

    for (int u = 0; u < nu; ++u) {
        const ushort* Au = Hall + (size_t)u * mc * 1024;
        const ushort* Bu = WD + (size_t)(unit_base + u) * UNIT_W;
        for (int kk = 0; kk < 1024; kk += 64) {
#pragma unroll
            for (int j = 0; j < 4; ++j) {
                int q = w * 4 + j;
                int c = q * 64 + l;
                int row = c >> 3, pc = c & 7;
                int lc = pc ^ (row & 7);
                gload_lds16(Au + (size_t)(bm + row) * 1024 + kk + lc * 8, lsA + q * 512);
            }
#pragma unroll
            for (int j = 0; j < BCH; ++j) {
                int q = w * BCH + j;
                int c = q * 64 + l;
                int row = c >> 3, pc = c & 7;
                int lc = pc ^ (row & 7);
                gload_lds16(Bu + (size_t)(bn + row) * 1024 + kk + lc * 8, lsB + q * 512);
            }
            __syncthreads();
#pragma unroll
            for (int s = 0; s < 2; ++s) {
                bf16x8 af[4], bfr[NI];
#pragma unroll
                for (int i = 0; i < 4; ++i) {
                    int ar = wm * 64 + i * 16 + (l & 15);
                    int lcr = s * 4 + (l >> 4);
                    af[i] = *reinterpret_cast<const bf16x8*>(&lsA[ar * 64 + ((lcr ^ (ar & 7)) * 8)]);
                }
#pragma unroll
                for (int i = 0; i < NI; ++i) {
                    int br = wn * WN + i * 16 + (l & 15);
                    int lcr = s * 4 + (l >> 4);
                    bfr[i] = *reinterpret_cast<const bf16x8*>(&lsB[br * 64 + ((lcr ^ (br & 7)) * 8)]);
                }
#pragma unroll
                for (int mi = 0; mi < 4; ++mi)
#pragma unroll
                    for (int ni = 0; ni < NI; ++ni)
                        acc[mi][ni] = mfma16(af[mi], bfr[ni], acc[mi][ni]);
            }
            __syncthreads();
        }
    }

    const int b = (m_base + bm) >> 10;
#pragma unroll
    for (int ni = 0; ni < NI; ++ni) {
        int col = bn + wn * WN + ni * 16 + (l & 15);
        float bias = 0.0f;
        if (!accumulate) {
            bias = bsd[col];
#pragma unroll
            for (int e = 0; e < 8; ++e)
                bias += rw[b * 8 + e] * brd[e * 512 + col];
        }
#pragma unroll
        for (int mi = 0; mi < 4; ++mi)
#pragma unroll
            for (int r = 0; r < 4; ++r) {
                int grow = m_base + bm + wm * 64 + mi * 16 + (l >> 4) * 4 + r;
                if (accumulate) out[(size_t)grow * 512 + col] += acc[mi][ni][r];
                else            out[(size_t)grow * 512 + col]  = acc[mi][ni][r] + bias;
            }
    }
}

// ---------- launch ----------
extern "C" void kernel_launch(void* const* d_in, const int* in_sizes, int n_in,
                              void* d_out, int out_size, void* d_ws, size_t ws_size,
                              hipStream_t stream) {
    const float* x   = (const float*)d_in[0];
    const float* rw  = (const float*)d_in[1];
    const float* Wsg = (const float*)d_in[2];
    const float* bsg = (const float*)d_in[3];
    const float* Wsu = (const float*)d_in[4];
    const float* bsu = (const float*)d_in[5];
    const float* Wsd = (const float*)d_in[6];
    const float* bsd = (const float*)d_in[7];
    const float* Wrg = (const float*)d_in[8];
    const float* brg = (const float*)d_in[9];
    const float* Wru = (const float*)d_in[10];
    const float* bru = (const float*)d_in[11];
    const float* Wrd = (const float*)d_in[12];
    const float* brd = (const float*)d_in[13];
    float* out = (float*)d_out;

    const size_t xb_b = (size_t)M_TOT * 512 * 2;            // 16.8 MB
    const size_t w_b  = (size_t)N_UNITS * UNIT_W * 2;       // 10.5 MB each

    char* ws = (char*)d_ws;
    ushort* xb  = (ushort*)ws; ws += xb_b;
    ushort* wgT = (ushort*)ws; ws += w_b;
    ushort* wuT = (ushort*)ws; ws += w_b;
    ushort* wdT = (ushort*)ws; ws += w_b;
    ushort* Hb  = (ushort*)ws;

    const size_t base_b = xb_b + 3 * w_b;
    const size_t hall16 = (size_t)N_UNITS * 16384 * 1024 * 2;  // 335.5 MB
    const size_t hall8  = (size_t)N_UNITS * 8192 * 1024 * 2;   // 167.8 MB

    k_cvt_x<<<8192, 256, 0, stream>>>(x, xb);
    k_trans<512, 1024, 0><<<dim3(16, 8, 10), 256, 0, stream>>>(Wsg, Wrg, wgT);
    k_trans<512, 1024, 0><<<dim3(16, 8, 10), 256, 0, stream>>>(Wsu, Wru, wuT);
    k_trans<1024, 512, 1><<<dim3(8, 16, 10), 256, 0, stream>>>(Wsd, Wrd, wdT);

    if (ws_size >= base_b + hall16) {
        // single chunk: full fusion, no RMW
        gemm_gateup2<<<10240, 256, 0, stream>>>(xb, wgT, wuT, bsg, bsu, brg, bru, rw, Hb,
                                                0, 0, 16384, 10);
        gemm_down2<128><<<512, 256, 0, stream>>>(Hb, wdT, bsd, brd, rw, out,
                                                 N_UNITS, 0, 0, 16384, 0);
    } else if (ws_size >= base_b + hall8) {
        // two M-chunks of 8192 rows, no RMW; down tile 128x64 keeps grid at 512
        for (int ch = 0; ch < 2; ++ch) {
            gemm_gateup2<<<5120, 256, 0, stream>>>(xb, wgT, wuT, bsg, bsu, brg, bru, rw, Hb,
                                                   0, ch * 8192, 8192, 9);
            gemm_down2<64><<<512, 256, 0, stream>>>(Hb, wdT, bsd, brd, rw, out,
                                                    N_UNITS, 0, ch * 8192, 8192, 0);
        }
    } else {
        // per-unit fallback: first down writes (bias folded), rest accumulate
        for (int u = 0; u < N_UNITS; ++u) {
            gemm_gateup2<<<1024, 256, 0, stream>>>(xb, wgT, wuT, bsg, bsu, brg, bru, rw, Hb,
                                                   u, 0, 16384, 10);
            gemm_down2<128><<<512, 256, 0, stream>>>(Hb, wdT, bsd, brd, rw, out,
                                                     1, u, 0, 16384, u > 0 ? 1 : 0);
        }
    }
}

// Round 12
// 703.713 us; speedup vs baseline: 1.4384x; 1.0793x over previous
//
#include <hip/hip_runtime.h>

// ---------- types ----------
typedef __bf16 bf16_t;
typedef bf16_t bf16x8 __attribute__((ext_vector_type(8)));
typedef float f32x4 __attribute__((ext_vector_type(4)));

__device__ inline f32x4 mfma16(bf16x8 a, bf16x8 b, f32x4 c) {
    return __builtin_amdgcn_mfma_f32_16x16x32_bf16(a, b, c, 0, 0, 0);
}

__device__ inline ushort f2bf(float f) {
    unsigned u = __builtin_bit_cast(unsigned, f);
    unsigned r = (u + 0x7FFFu + ((u >> 16) & 1u)) >> 16;
    return (ushort)r;
}

__device__ inline void gload_lds16(const void* g, void* l) {
    __builtin_amdgcn_global_load_lds(
        (const __attribute__((address_space(1))) void*)g,
        (__attribute__((address_space(3))) void*)l, 16, 0, 0);
}

// ---------- problem constants ----------
// B=16, Ktok=1024, D=512, HS=2048, HR=1024, E=8
// M=16384; units 0,1 = shared halves (scale 1), 2..9 = experts (scale rw[b,e])
#define M_TOT 16384
#define N_UNITS 10
#define UNIT_W (1024*512)
#define UNIT_W2 (2048*512)

// ---------- conversion kernels ----------
__global__ void k_cvt_x(const float* __restrict__ x, ushort* __restrict__ xb) {
    int i = (blockIdx.x * 256 + threadIdx.x) * 4;
    float4 v = *reinterpret_cast<const float4*>(x + i);
    ushort4 o;
    o.x = f2bf(v.x); o.y = f2bf(v.y); o.z = f2bf(v.z); o.w = f2bf(v.w);
    *reinterpret_cast<ushort4*>(xb + i) = o;
}

// gate/up -> merged-interleaved W2 [10][2048][512] bf16 (N-major).
// comb row n for real col c: n = (c>>4)*32 + IS_UP*16 + (c&15).
template<int IS_UP>
__global__ void k_trans2(const float* __restrict__ Wsh, const float* __restrict__ Wrt,
                         ushort* __restrict__ W2) {
    int u = blockIdx.z;
    const float* src; int stride;
    if (u < 2) { src = Wsh + u * 1024; stride = 2048; }
    else       { src = Wrt + (size_t)(u - 2) * 512 * 1024; stride = 1024; }
    __shared__ float t[64][65];
    int r0 = blockIdx.y * 64, c0 = blockIdx.x * 64;   // r0: k rows, c0: real cols
    int tid = threadIdx.x;
#pragma unroll
    for (int i = 0; i < 16; ++i) {
        int idx = i * 256 + tid;
        int r = idx >> 6, c = idx & 63;
        t[r][c] = src[(r0 + r) * stride + c0 + c];
    }
    __syncthreads();
    ushort* d = W2 + (size_t)u * UNIT_W2;
#pragma unroll
    for (int i = 0; i < 16; ++i) {
        int idx = i * 256 + tid;
        int r = idx >> 6, c = idx & 63;    // (c0+r)=real col, (r0+c)=k
        int rc = c0 + r;
        int n = ((rc >> 4) << 5) + IS_UP * 16 + (rc & 15);
        d[(size_t)n * 512 + (r0 + c)] = f2bf(t[c][r]);
    }
}

// down weights: transpose [ROWS x COLS] f32 -> [COLS x ROWS] bf16 (N-major)
template<int ROWS, int COLS>
__global__ void k_transD(const float* __restrict__ Wsh, const float* __restrict__ Wrt,
                         ushort* __restrict__ dst) {
    int u = blockIdx.z;
    const float* src = (u < 2) ? (Wsh + (size_t)u * ROWS * COLS)
                               : (Wrt + (size_t)(u - 2) * ROWS * COLS);
    int stride = COLS;
    __shared__ float t[64][65];
    int r0 = blockIdx.y * 64, c0 = blockIdx.x * 64;
    int tid = threadIdx.x;
#pragma unroll
    for (int i = 0; i < 16; ++i) {
        int idx = i * 256 + tid;
        int r = idx >> 6, c = idx & 63;
        t[r][c] = src[(r0 + r) * stride + c0 + c];
    }
    __syncthreads();
    ushort* d = dst + (size_t)u * ROWS * COLS;
#pragma unroll
    for (int i = 0; i < 16; ++i) {
        int idx = i * 256 + tid;
        int r = idx >> 6, c = idx & 63;
        d[(size_t)(c0 + r) * ROWS + (r0 + c)] = f2bf(t[c][r]);
    }
}

// ---------- GEMM 1: merged gate+up + SwiGLU. BK=64, XOR-swizzled LDS ----------
// A [M][512] bf16; W2 [10][2048][512] bf16; Hall [nu][M][1024] bf16.
// Block 128M x 128comb (=64 H cols), 4 waves (2x2), wave 64x64comb, acc[4][4].
// grid = nu * 128 * 16; block/unit = 2048 (ul = swz>>11).
__global__ __launch_bounds__(256, 2) void gemm_gu3(
    const ushort* __restrict__ A, const ushort* __restrict__ W2,
    const float* __restrict__ bsg, const float* __restrict__ bsu,
    const float* __restrict__ brg, const float* __restrict__ bru,
    const float* __restrict__ rw, ushort* __restrict__ Hall, int unit_base) {
    __shared__ ushort lsA[128 * 64];
    __shared__ ushort lsB[128 * 64];
    const int nwg = gridDim.x, cpx = nwg >> 3;
    const int lid = blockIdx.x;
    const int swz = (lid & 7) * cpx + (lid >> 3);   // bijective: nwg % 8 == 0
    const int ul = swz >> 11;
    const int rem = swz & 2047;
    const int bm = (rem >> 4) * 128;     // M rows
    const int bnc = (rem & 15) * 128;    // combined col base
    const int ug = unit_base + ul;
    const ushort* Bw = W2 + (size_t)ug * UNIT_W2;

    const int tid = threadIdx.x;
    const int l = tid & 63, w = tid >> 6;
    const int wm = w >> 1, wn = w & 1;

    f32x4 acc[4][4] = {};

    for (int kk = 0; kk < 512; kk += 64) {
#pragma unroll
        for (int j = 0; j < 4; ++j) {
            int q = w * 4 + j;            // 1KB block 0..15
            int c = q * 64 + l;           // 16B chunk 0..1023
            int row = c >> 3, pc = c & 7;
            int lc = pc ^ (row & 7);      // source k-chunk (inverse swizzle)
            int koff = kk + lc * 8;
            gload_lds16(A  + (size_t)(bm + row) * 512 + koff,  lsA + q * 512);
            gload_lds16(Bw + (size_t)(bnc + row) * 512 + koff, lsB + q * 512);
        }
        __syncthreads();
#pragma unroll
        for (int s = 0; s < 2; ++s) {
            bf16x8 af[4], bf[4];
            int lcr = s * 4 + (l >> 4);
#pragma unroll
            for (int i = 0; i < 4; ++i) {
                int ar = wm * 64 + i * 16 + (l & 15);
                int br = wn * 64 + i * 16 + (l & 15);
                af[i] = *reinterpret_cast<const bf16x8*>(&lsA[ar * 64 + ((lcr ^ (ar & 7)) * 8)]);
                bf[i] = *reinterpret_cast<const bf16x8*>(&lsB[br * 64 + ((lcr ^ (br & 7)) * 8)]);
            }
#pragma unroll
            for (int mi = 0; mi < 4; ++mi)
#pragma unroll
                for (int ni = 0; ni < 4; ++ni)
                    acc[mi][ni] = mfma16(af[mi], bf[ni], acc[mi][ni]);
        }
        __syncthreads();
    }

    const float* bg = (ug < 2) ? (bsg + ug * 1024) : (brg + (ug - 2) * 1024);
    const float* bu = (ug < 2) ? (bsu + ug * 1024) : (bru + (ug - 2) * 1024);
    const float scale = (ug < 2) ? 1.0f : rw[(bm >> 10) * 8 + (ug - 2)];
    ushort* H = Hall + (size_t)ul * M_TOT * 1024;
#pragma unroll
    for (int p = 0; p < 2; ++p) {
        int colH = ((bnc + wn * 64) >> 1) + p * 16 + (l & 15);
        float bgv = bg[colH], buv = bu[colH];
#pragma unroll
        for (int mi = 0; mi < 4; ++mi)
#pragma unroll
            for (int r = 0; r < 4; ++r) {
                int row = bm + wm * 64 + mi * 16 + (l >> 4) * 4 + r;
                float g = acc[mi][2 * p][r] + bgv;
                float uu = acc[mi][2 * p + 1][r] + buv;
                float h = g / (1.0f + __expf(-g)) * uu * scale;
                H[(size_t)row * 1024 + colH] = f2bf(h);
            }
    }
}

// ---------- GEMM 2: down, multi-unit register-accumulated K, BK=64, swizzled ----------
// Hall [nu][M][1024] bf16; WD [10][512][1024] bf16; out [M][512] f32.
// Block 128x64, 4 waves (2x2), wave 64x32, acc[4][2]. grid = 128*8 = 1024 (4/CU).
__global__ __launch_bounds__(256, 2) void gemm_dn3(
    const ushort* __restrict__ Hall, const ushort* __restrict__ WD,
    const float* __restrict__ bsd, const float* __restrict__ brd,
    const float* __restrict__ rw, float* __restrict__ out,
    int nu, int unit_base, int accumulate) {
    __shared__ ushort lsA[128 * 64];
    __shared__ ushort lsB[64 * 64];
    const int nwg = gridDim.x, cpx = nwg >> 3;
    const int lid = blockIdx.x;
    const int swz = (lid & 7) * cpx + (lid >> 3);
    const int bm = (swz >> 3) * 128;
    const int bn = (swz & 7) * 64;

    const int tid = threadIdx.x;
    const int l = tid & 63, w = tid >> 6;
    const int wm = w >> 1, wn = w & 1;

    f32x4 acc[4][2] = {};

    for (int u = 0; u < nu; ++u) {
        const ushort* Au = Hall + (size_t)u * M_TOT * 1024;
        const ushort* Bu = WD + (size_t)(unit_base + u) * UNIT_W;
        for (int kk = 0; kk < 1024; kk += 64) {
#pragma unroll
            for (int j = 0; j < 4; ++j) {
                int q = w * 4 + j;
                int c = q * 64 + l;
                int row = c >> 3, pc = c & 7;
                int lc = pc ^ (row & 7);
                gload_lds16(Au + (size_t)(bm + row) * 1024 + kk + lc * 8, lsA + q * 512);
            }
#pragma unroll
            for (int j = 0; j < 2; ++j) {
                int q = w * 2 + j;
                int c = q * 64 + l;
                int row = c >> 3, pc = c & 7;
                int lc = pc ^ (row & 7);
                gload_lds16(Bu + (size_t)(bn + row) * 1024 + kk + lc * 8, lsB + q * 512);
            }
            __syncthreads();
#pragma unroll
            for (int s = 0; s < 2; ++s) {
                bf16x8 af[4], bfr[2];
                int lcr = s * 4 + (l >> 4);
#pragma unroll
                for (int i = 0; i < 4; ++i) {
                    int ar = wm * 64 + i * 16 + (l & 15);
                    af[i] = *reinterpret_cast<const bf16x8*>(&lsA[ar * 64 + ((lcr ^ (ar & 7)) * 8)]);
                }
#pragma unroll
                for (int i = 0; i < 2; ++i) {
                    int br = wn * 32 + i * 16 + (l & 15);
                    bfr[i] = *reinterpret_cast<const bf16x8*>(&lsB[br * 64 + ((lcr ^ (br & 7)) * 8)]);
                }
#pragma unroll
                for (int mi = 0; mi < 4; ++mi)
#pragma unroll
                    for (int ni = 0; ni < 2; ++ni)
                        acc[mi][ni] = mfma16(af[mi], bfr[ni], acc[mi][ni]);
            }
            __syncthreads();
        }
    }

    const int b = bm >> 10;
#pragma unroll
    for (int ni = 0; ni < 2; ++ni) {
        int col = bn + wn * 32 + ni * 16 + (l & 15);
        float bias = 0.0f;
        if (!accumulate) {
            bias = bsd[col];
#pragma unroll
            for (int e = 0; e < 8; ++e)
                bias += rw[b * 8 + e] * brd[e * 512 + col];
        }
#pragma unroll
        for (int mi = 0; mi < 4; ++mi)
#pragma unroll
            for (int r = 0; r < 4; ++r) {
                int grow = bm + wm * 64 + mi * 16 + (l >> 4) * 4 + r;
                if (accumulate) out[(size_t)grow * 512 + col] += acc[mi][ni][r];
                else            out[(size_t)grow * 512 + col]  = acc[mi][ni][r] + bias;
            }
    }
}

// ---------- launch ----------
extern "C" void kernel_launch(void* const* d_in, const int* in_sizes, int n_in,
                              void* d_out, int out_size, void* d_ws, size_t ws_size,
                              hipStream_t stream) {
    const float* x   = (const float*)d_in[0];
    const float* rw  = (const float*)d_in[1];
    const float* Wsg = (const float*)d_in[2];
    const float* bsg = (const float*)d_in[3];
    const float* Wsu = (const float*)d_in[4];
    const float* bsu = (const float*)d_in[5];
    const float* Wsd = (const float*)d_in[6];
    const float* bsd = (const float*)d_in[7];
    const float* Wrg = (const float*)d_in[8];
    const float* brg = (const float*)d_in[9];
    const float* Wru = (const float*)d_in[10];
    const float* bru = (const float*)d_in[11];
    const float* Wrd = (const float*)d_in[12];
    const float* brd = (const float*)d_in[13];
    float* out = (float*)d_out;

    const size_t xb_b  = (size_t)M_TOT * 512 * 2;              // 16.8 MB
    const size_t w2_b  = (size_t)N_UNITS * UNIT_W2 * 2;        // 21.0 MB
    const size_t wd_b  = (size_t)N_UNITS * UNIT_W * 2;         // 10.5 MB

    char* ws = (char*)d_ws;
    ushort* xb  = (ushort*)ws; ws += xb_b;
    ushort* W2  = (ushort*)ws; ws += w2_b;
    ushort* wdT = (ushort*)ws; ws += wd_b;
    ushort* Hb  = (ushort*)ws;

    const size_t base_b = xb_b + w2_b + wd_b;
    const size_t hall5 = (size_t)5 * M_TOT * 1024 * 2;   // 167.8 MB
    const size_t hall1 = (size_t)M_TOT * 1024 * 2;       // 33.5 MB

    k_cvt_x<<<8192, 256, 0, stream>>>(x, xb);
    k_trans2<0><<<dim3(16, 8, 10), 256, 0, stream>>>(Wsg, Wrg, W2);
    k_trans2<1><<<dim3(16, 8, 10), 256, 0, stream>>>(Wsu, Wru, W2);
    k_transD<1024, 512><<<dim3(8, 16, 10), 256, 0, stream>>>(Wsd, Wrd, wdT);

    if (ws_size >= base_b + hall5) {
        // two unit-groups of 5, full-M Hall; second down accumulates (one RMW)
        for (int g = 0; g < 2; ++g) {
            gemm_gu3<<<10240, 256, 0, stream>>>(xb, W2, bsg, bsu, brg, bru, rw, Hb, g * 5);
            gemm_dn3<<<1024, 256, 0, stream>>>(Hb, wdT, bsd, brd, rw, out, 5, g * 5, g);
        }
    } else {
        // per-unit fallback
        for (int u = 0; u < N_UNITS; ++u) {
            gemm_gu3<<<2048, 256, 0, stream>>>(xb, W2, bsg, bsu, brg, bru, rw, Hb, u);
            gemm_dn3<<<1024, 256, 0, stream>>>(Hb, wdT, bsd, brd, rw, out, 1, u, u > 0 ? 1 : 0);
        }
    }
}

// Round 14
// 697.761 us; speedup vs baseline: 1.4506x; 1.0085x over previous
//
#include <hip/hip_runtime.h>

// ---------- types ----------
typedef __bf16 bf16_t;
typedef bf16_t bf16x8 __attribute__((ext_vector_type(8)));
typedef float f32x4 __attribute__((ext_vector_type(4)));

__device__ inline f32x4 mfma16(bf16x8 a, bf16x8 b, f32x4 c) {
    return __builtin_amdgcn_mfma_f32_16x16x32_bf16(a, b, c, 0, 0, 0);
}

__device__ inline ushort f2bf(float f) {
    unsigned u = __builtin_bit_cast(unsigned, f);
    unsigned r = (u + 0x7FFFu + ((u >> 16) & 1u)) >> 16;
    return (ushort)r;
}

__device__ inline void gload_lds16(const void* g, void* l) {
    __builtin_amdgcn_global_load_lds(
        (const __attribute__((address_space(1))) void*)g,
        (__attribute__((address_space(3))) void*)l, 16, 0, 0);
}

// ---------- problem constants ----------
// B=16, Ktok=1024, D=512, HS=2048, HR=1024, E=8
// M=16384; units 0,1 = shared halves (scale 1), 2..9 = experts (scale rw[b,e])
#define M_TOT 16384
#define N_UNITS 10
#define UNIT_W (1024*512)
#define UNIT_W2 (2048*512)

// ---------- conversion kernels ----------
__global__ void k_cvt_x(const float* __restrict__ x, ushort* __restrict__ xb) {
    int i = (blockIdx.x * 256 + threadIdx.x) * 4;
    float4 v = *reinterpret_cast<const float4*>(x + i);
    ushort4 o;
    o.x = f2bf(v.x); o.y = f2bf(v.y); o.z = f2bf(v.z); o.w = f2bf(v.w);
    *reinterpret_cast<ushort4*>(xb + i) = o;
}

// gate/up -> merged-interleaved W2 [10][2048][512] bf16 (N-major).
// comb row n for real col c: n = (c>>4)*32 + IS_UP*16 + (c&15).
template<int IS_UP>
__global__ void k_trans2(const float* __restrict__ Wsh, const float* __restrict__ Wrt,
                         ushort* __restrict__ W2) {
    int u = blockIdx.z;
    const float* src; int stride;
    if (u < 2) { src = Wsh + u * 1024; stride = 2048; }
    else       { src = Wrt + (size_t)(u - 2) * 512 * 1024; stride = 1024; }
    __shared__ float t[64][65];
    int r0 = blockIdx.y * 64, c0 = blockIdx.x * 64;   // r0: k rows, c0: real cols
    int tid = threadIdx.x;
#pragma unroll
    for (int i = 0; i < 16; ++i) {
        int idx = i * 256 + tid;
        int r = idx >> 6, c = idx & 63;
        t[r][c] = src[(r0 + r) * stride + c0 + c];
    }
    __syncthreads();
    ushort* d = W2 + (size_t)u * UNIT_W2;
#pragma unroll
    for (int i = 0; i < 16; ++i) {
        int idx = i * 256 + tid;
        int r = idx >> 6, c = idx & 63;    // (c0+r)=real col, (r0+c)=k
        int rc = c0 + r;
        int n = ((rc >> 4) << 5) + IS_UP * 16 + (rc & 15);
        d[(size_t)n * 512 + (r0 + c)] = f2bf(t[c][r]);
    }
}

// down weights: transpose [ROWS x COLS] f32 -> [COLS x ROWS] bf16 (N-major)
template<int ROWS, int COLS>
__global__ void k_transD(const float* __restrict__ Wsh, const float* __restrict__ Wrt,
                         ushort* __restrict__ dst) {
    int u = blockIdx.z;
    const float* src = (u < 2) ? (Wsh + (size_t)u * ROWS * COLS)
                               : (Wrt + (size_t)(u - 2) * ROWS * COLS);
    int stride = COLS;
    __shared__ float t[64][65];
    int r0 = blockIdx.y * 64, c0 = blockIdx.x * 64;
    int tid = threadIdx.x;
#pragma unroll
    for (int i = 0; i < 16; ++i) {
        int idx = i * 256 + tid;
        int r = idx >> 6, c = idx & 63;
        t[r][c] = src[(r0 + r) * stride + c0 + c];
    }
    __syncthreads();
    ushort* d = dst + (size_t)u * ROWS * COLS;
#pragma unroll
    for (int i = 0; i < 16; ++i) {
        int idx = i * 256 + tid;
        int r = idx >> 6, c = idx & 63;
        d[(size_t)(c0 + r) * ROWS + (r0 + c)] = f2bf(t[c][r]);
    }
}

// ---------- GEMM 1: merged gate+up + SwiGLU. BK=64, XOR-swizzled LDS ----------
// A [M][512] bf16; W2 [10][2048][512] bf16; Hall [nu][M][1024] bf16.
// Block 128M x 128comb (=64 H cols), 4 waves (2x2), wave 64x64comb, acc[4][4].
// grid = nu * 128 * 16; block/unit = 2048 (ul = swz>>11).
__global__ __launch_bounds__(256, 2) void gemm_gu3(
    const ushort* __restrict__ A, const ushort* __restrict__ W2,
    const float* __restrict__ bsg, const float* __restrict__ bsu,
    const float* __restrict__ brg, const float* __restrict__ bru,
    const float* __restrict__ rw, ushort* __restrict__ Hall, int unit_base) {
    __shared__ ushort lsA[128 * 64];
    __shared__ ushort lsB[128 * 64];
    const int nwg = gridDim.x, cpx = nwg >> 3;
    const int lid = blockIdx.x;
    const int swz = (lid & 7) * cpx + (lid >> 3);   // bijective: nwg % 8 == 0
    const int ul = swz >> 11;
    const int rem = swz & 2047;
    const int bm = (rem >> 4) * 128;     // M rows
    const int bnc = (rem & 15) * 128;    // combined col base
    const int ug = unit_base + ul;
    const ushort* Bw = W2 + (size_t)ug * UNIT_W2;

    const int tid = threadIdx.x;
    const int l = tid & 63, w = tid >> 6;
    const int wm = w >> 1, wn = w & 1;

    f32x4 acc[4][4] = {};

    for (int kk = 0; kk < 512; kk += 64) {
#pragma unroll
        for (int j = 0; j < 4; ++j) {
            int q = w * 4 + j;            // 1KB block 0..15
            int c = q * 64 + l;           // 16B chunk 0..1023
            int row = c >> 3, pc = c & 7;
            int lc = pc ^ (row & 7);      // source k-chunk (inverse swizzle)
            int koff = kk + lc * 8;
            gload_lds16(A  + (size_t)(bm + row) * 512 + koff,  lsA + q * 512);
            gload_lds16(Bw + (size_t)(bnc + row) * 512 + koff, lsB + q * 512);
        }
        __syncthreads();
#pragma unroll
        for (int s = 0; s < 2; ++s) {
            bf16x8 af[4], bf[4];
            int lcr = s * 4 + (l >> 4);
#pragma unroll
            for (int i = 0; i < 4; ++i) {
                int ar = wm * 64 + i * 16 + (l & 15);
                int br = wn * 64 + i * 16 + (l & 15);
                af[i] = *reinterpret_cast<const bf16x8*>(&lsA[ar * 64 + ((lcr ^ (ar & 7)) * 8)]);
                bf[i] = *reinterpret_cast<const bf16x8*>(&lsB[br * 64 + ((lcr ^ (br & 7)) * 8)]);
            }
#pragma unroll
            for (int mi = 0; mi < 4; ++mi)
#pragma unroll
                for (int ni = 0; ni < 4; ++ni)
                    acc[mi][ni] = mfma16(af[mi], bf[ni], acc[mi][ni]);
        }
        __syncthreads();
    }

    const float* bg = (ug < 2) ? (bsg + ug * 1024) : (brg + (ug - 2) * 1024);
    const float* bu = (ug < 2) ? (bsu + ug * 1024) : (bru + (ug - 2) * 1024);
    const float scale = (ug < 2) ? 1.0f : rw[(bm >> 10) * 8 + (ug - 2)];
    ushort* H = Hall + (size_t)ul * M_TOT * 1024;
#pragma unroll
    for (int p = 0; p < 2; ++p) {
        int colH = ((bnc + wn * 64) >> 1) + p * 16 + (l & 15);
        float bgv = bg[colH], buv = bu[colH];
#pragma unroll
        for (int mi = 0; mi < 4; ++mi)
#pragma unroll
            for (int r = 0; r < 4; ++r) {
                int row = bm + wm * 64 + mi * 16 + (l >> 4) * 4 + r;
                float g = acc[mi][2 * p][r] + bgv;
                float uu = acc[mi][2 * p + 1][r] + buv;
                float h = g / (1.0f + __expf(-g)) * uu * scale;
                H[(size_t)row * 1024 + colH] = f2bf(h);
            }
    }
}

// ---------- GEMM 2: down, TN=128 (gu3-shape), multi-unit K, BK=64, swizzled ----------
// Hall [nu][M][1024] bf16; WD [10][512][1024] bf16; out [M][512] f32.
// Block 128x128, 4 waves (2x2), wave 64x64, acc[4][4]. grid = 128*4 = 512.
// Per K-step: 8 gload + 16 ds_read + 32 MFMA (same density as gu3 -> ~900 TF).
__global__ __launch_bounds__(256, 2) void gemm_dn4(
    const ushort* __restrict__ Hall, const ushort* __restrict__ WD,
    const float* __restrict__ bsd, const float* __restrict__ brd,
    const float* __restrict__ rw, float* __restrict__ out,
    int nu, int unit_base, int accumulate) {
    __shared__ ushort lsA[128 * 64];
    __shared__ ushort lsB[128 * 64];
    const int nwg = gridDim.x, cpx = nwg >> 3;
    const int lid = blockIdx.x;
    const int swz = (lid & 7) * cpx + (lid >> 3);
    const int bm = (swz >> 2) * 128;   // 128 M-tiles
    const int bn = (swz & 3) * 128;    // 4 N-tiles

    const int tid = threadIdx.x;
    const int l = tid & 63, w = tid >> 6;
    const int wm = w >> 1, wn = w & 1;

    f32x4 acc[4][4] = {};

    for (int u = 0; u < nu; ++u) {
        const ushort* Au = Hall + (size_t)u * M_TOT * 1024;
        const ushort* Bu = WD + (size_t)(unit_base + u) * UNIT_W;
        for (int kk = 0; kk < 1024; kk += 64) {
#pragma unroll
            for (int j = 0; j < 4; ++j) {
                int q = w * 4 + j;
                int c = q * 64 + l;
                int row = c >> 3, pc = c & 7;
                int lc = pc ^ (row & 7);
                int koff = kk + lc * 8;
                gload_lds16(Au + (size_t)(bm + row) * 1024 + koff, lsA + q * 512);
                gload_lds16(Bu + (size_t)(bn + row) * 1024 + koff, lsB + q * 512);
            }
            __syncthreads();
#pragma unroll
            for (int s = 0; s < 2; ++s) {
                bf16x8 af[4], bfr[4];
                int lcr = s * 4 + (l >> 4);
#pragma unroll
                for (int i = 0; i < 4; ++i) {
                    int ar = wm * 64 + i * 16 + (l & 15);
                    int br = wn * 64 + i * 16 + (l & 15);
                    af[i] = *reinterpret_cast<const bf16x8*>(&lsA[ar * 64 + ((lcr ^ (ar & 7)) * 8)]);
                    bfr[i] = *reinterpret_cast<const bf16x8*>(&lsB[br * 64 + ((lcr ^ (br & 7)) * 8)]);
                }
#pragma unroll
                for (int mi = 0; mi < 4; ++mi)
#pragma unroll
                    for (int ni = 0; ni < 4; ++ni)
                        acc[mi][ni] = mfma16(af[mi], bfr[ni], acc[mi][ni]);
            }
            __syncthreads();
        }
    }

    const int b = bm >> 10;
#pragma unroll
    for (int ni = 0; ni < 4; ++ni) {
        int col = bn + wn * 64 + ni * 16 + (l & 15);
        float bias = 0.0f;
        if (!accumulate) {
            bias = bsd[col];
#pragma unroll
            for (int e = 0; e < 8; ++e)
                bias += rw[b * 8 + e] * brd[e * 512 + col];
        }
#pragma unroll
        for (int mi = 0; mi < 4; ++mi)
#pragma unroll
            for (int r = 0; r < 4; ++r) {
                int grow = bm + wm * 64 + mi * 16 + (l >> 4) * 4 + r;
                if (accumulate) out[(size_t)grow * 512 + col] += acc[mi][ni][r];
                else            out[(size_t)grow * 512 + col]  = acc[mi][ni][r] + bias;
            }
    }
}

// ---------- launch ----------
extern "C" void kernel_launch(void* const* d_in, const int* in_sizes, int n_in,
                              void* d_out, int out_size, void* d_ws, size_t ws_size,
                              hipStream_t stream) {
    const float* x   = (const float*)d_in[0];
    const float* rw  = (const float*)d_in[1];
    const float* Wsg = (const float*)d_in[2];
    const float* bsg = (const float*)d_in[3];
    const float* Wsu = (const float*)d_in[4];
    const float* bsu = (const float*)d_in[5];
    const float* Wsd = (const float*)d_in[6];
    const float* bsd = (const float*)d_in[7];
    const float* Wrg = (const float*)d_in[8];
    const float* brg = (const float*)d_in[9];
    const float* Wru = (const float*)d_in[10];
    const float* bru = (const float*)d_in[11];
    const float* Wrd = (const float*)d_in[12];
    const float* brd = (const float*)d_in[13];
    float* out = (float*)d_out;

    const size_t xb_b  = (size_t)M_TOT * 512 * 2;              // 16.8 MB
    const size_t w2_b  = (size_t)N_UNITS * UNIT_W2 * 2;        // 21.0 MB
    const size_t wd_b  = (size_t)N_UNITS * UNIT_W * 2;         // 10.5 MB

    char* ws = (char*)d_ws;
    ushort* xb  = (ushort*)ws; ws += xb_b;
    ushort* W2  = (ushort*)ws; ws += w2_b;
    ushort* wdT = (ushort*)ws; ws += wd_b;
    ushort* Hb  = (ushort*)ws;

    const size_t base_b = xb_b + w2_b + wd_b;
    const size_t hall5 = (size_t)5 * M_TOT * 1024 * 2;   // 167.8 MB

    k_cvt_x<<<8192, 256, 0, stream>>>(x, xb);
    k_trans2<0><<<dim3(16, 8, 10), 256, 0, stream>>>(Wsg, Wrg, W2);
    k_trans2<1><<<dim3(16, 8, 10), 256, 0, stream>>>(Wsu, Wru, W2);
    k_transD<1024, 512><<<dim3(8, 16, 10), 256, 0, stream>>>(Wsd, Wrd, wdT);

    if (ws_size >= base_b + hall5) {
        // two unit-groups of 5, full-M Hall; second down accumulates (one RMW)
        for (int g = 0; g < 2; ++g) {
            gemm_gu3<<<10240, 256, 0, stream>>>(xb, W2, bsg, bsu, brg, bru, rw, Hb, g * 5);
            gemm_dn4<<<512, 256, 0, stream>>>(Hb, wdT, bsd, brd, rw, out, 5, g * 5, g);
        }
    } else {
        // per-unit fallback
        for (int u = 0; u < N_UNITS; ++u) {
            gemm_gu3<<<2048, 256, 0, stream>>>(xb, W2, bsg, bsu, brg, bru, rw, Hb, u);
            gemm_dn4<<<512, 256, 0, stream>>>(Hb, wdT, bsd, brd, rw, out, 1, u, u > 0 ? 1 : 0);
        }
    }
}